// Round 1
// baseline (105.067 us; speedup 1.0000x reference)
//
#include <hip/hip_runtime.h>
#include <hip/hip_bf16.h>

// MMD loss via bf16 MFMA Gram matrix — barrier-free LDS-free GEMM (R8 core),
// now with: 2x2 wave-tile blocks (L1 fragment sharing), panel-ordered block
// decode (L2 working-set = 512KB hot B-panel), and per-block partial stores
// (no single-address fp64 atomic serialization).
//
// Zc layout (R7): Zc[ck][row][32], stored quad = q ^ ((row>>1)&3); each mfma
// fragment = one contiguous coalesced 1KB block.
// Lessons: R4 no __threadfence in hot kernel; R5 no forced occupancy (spill);
// R6 no scattered vector loads; R3/R7 barrier-drain plateau.
//
// z = [xf; yf] (8192 x 256). result = (1/4096^2)*(8192*NSIG + sum_{i<j} 2 s_i s_j K_ij)
// ws: [0,4MiB) bf16 Zc; float norms[8192]; float partials[2080].

#define NSIG 5
#define CKS   262144                 // chunk stride in ushorts: 8192 rows * 32
#define NBLK2 2080                   // 64-supergrid triangle: 64*65/2

typedef __attribute__((ext_vector_type(8))) short short8;
typedef __attribute__((ext_vector_type(4))) float floatx4;

// ---- prep: (B,C,H,W) fp32 -> Zc chunked-swizzled bf16 + norms (unchanged) ----
__global__ __launch_bounds__(256) void prep_kernel(const float* __restrict__ x,
                                                   const float* __restrict__ y,
                                                   ushort* __restrict__ Zc,
                                                   float* __restrict__ norms) {
    const int bid = blockIdx.x;           // s(1) | b(2) | strip(6)
    const int t = threadIdx.x;
    const int s = bid >> 8;
    const int b = (bid >> 6) & 3;
    const int p0 = (bid & 63) << 4;
    const float* src = s ? y : x;
    const int n0 = (s << 12) + (b << 10) + p0;

    __shared__ float tile[256][17];

    const int cg = t >> 2;
    const int p4 = (t & 3) << 2;
#pragma unroll
    for (int pass = 0; pass < 4; ++pass) {
        const int c = cg + (pass << 6);
        const float4 v = *(const float4*)(src + (((size_t)((b << 8) + c)) << 10) + p0 + p4);
        tile[c][p4] = v.x; tile[c][p4 + 1] = v.y; tile[c][p4 + 2] = v.z; tile[c][p4 + 3] = v.w;
    }
    __syncthreads();

    const int r = t >> 4;
    const int q = t & 15;
    const int row = n0 + r;
    const int sw = (row >> 1) & 3;
    float nsum = 0.f;
#pragma unroll
    for (int h = 0; h < 2; ++h) {
        const int j = q + (h << 4);
        const int ck = j >> 2;
        const int sq = (j & 3) ^ sw;
        const int c0 = j << 3;
        uint pk[4];
#pragma unroll
        for (int jj = 0; jj < 4; ++jj) {
            const float f0 = tile[c0 + 2 * jj][r];
            const float f1 = tile[c0 + 2 * jj + 1][r];
            const __hip_bfloat16 h0 = __float2bfloat16(f0);
            const __hip_bfloat16 h1 = __float2bfloat16(f1);
            const float q0 = __bfloat162float(h0), q1 = __bfloat162float(h1);
            nsum = fmaf(q0, q0, nsum);
            nsum = fmaf(q1, q1, nsum);
            pk[jj] = (uint)(*(const ushort*)&h0) | ((uint)(*(const ushort*)&h1) << 16);
        }
        *(uint4*)(Zc + (size_t)ck * CKS + (size_t)row * 32 + (sq << 3)) =
            make_uint4(pk[0], pk[1], pk[2], pk[3]);
    }
#pragma unroll
    for (int off = 1; off < 16; off <<= 1) nsum += __shfl_xor(nsum, off, 32);
    if (q == 0) norms[row] = nsum;
}

// ---- GEMM: block = 2x2 wave-tiles (128x128), panel-ordered triangle decode ----
__global__ __launch_bounds__(256, 3) void gemm_epi(const ushort* __restrict__ Zc,
                                                   const float* __restrict__ norms,
                                                   const float* __restrict__ sigmas,
                                                   float* __restrict__ partials) {
    __shared__ float wsum[4];

    const int t = threadIdx.x;
    const int w = t >> 6, l = t & 63;

    // panel decode: panels p of 8 super-columns; P(p) = 32p^2 + 4p blocks before
    // panel p; within panel, column-major (column tj2 has tj2+1 blocks).
    const int lin = blockIdx.x;
    int p = (int)((-4.0f + sqrtf(16.0f + 128.0f * (float)lin)) * (1.0f / 64.0f));
    p = p < 0 ? 0 : (p > 7 ? 7 : p);
    while (p < 7 && 32 * (p + 1) * (p + 1) + 4 * (p + 1) <= lin) ++p;
    while (p > 0 && 32 * p * p + 4 * p > lin) --p;
    const int o = lin - (32 * p * p + 4 * p);
    int c = 7;
#pragma unroll
    for (int cc = 7; cc >= 1; --cc) {
        const int Q = cc * (8 * p + 1) + (cc * (cc - 1)) / 2;
        if (o < Q) c = cc - 1;
    }
    const int Qc = c * (8 * p + 1) + (c * (c - 1)) / 2;
    const int tj2 = 8 * p + c;
    const int ti2 = o - Qc;              // 0..tj2

    // wave -> 64x64 tile: ti = 2*ti2 + (w>>1), tj = 2*tj2 + (w&1)
    const int ti = (ti2 << 1) + (w >> 1);
    const int tj = (tj2 << 1) + (w & 1);
    const bool active = (ti <= tj);      // one lower-tri wave per diagonal block idles
    const bool diag = (ti == tj);

    const int i0 = ti << 6, j0 = tj << 6;
    const int m = l & 15, q = l >> 4;

    int offA[4], offB[4];
#pragma unroll
    for (int f = 0; f < 4; ++f) {
        const int ra = i0 + (f << 4) + m;
        offA[f] = (ra << 5) + (((q ^ ((ra >> 1) & 3))) << 3);
        const int rb = j0 + (f << 4) + m;
        offB[f] = (rb << 5) + (((q ^ ((rb >> 1) & 3))) << 3);
    }

    floatx4 accf[4][4];
#pragma unroll
    for (int fi = 0; fi < 4; ++fi)
#pragma unroll
        for (int fj = 0; fj < 4; ++fj) accf[fi][fj] = (floatx4){0.f, 0.f, 0.f, 0.f};

    float lsum = 0.f;
    if (active) {
        short8 curA[4], curB[4], nxtA[4], nxtB[4];
#pragma unroll
        for (int f = 0; f < 4; ++f) {
            curA[f] = *(const short8*)(Zc + offA[f]);
            curB[f] = *(const short8*)(Zc + offB[f]);
        }
#pragma unroll
        for (int ck = 0; ck < 8; ++ck) {
            if (ck < 7) {
                const size_t ko = (size_t)(ck + 1) * CKS;
#pragma unroll
                for (int f = 0; f < 4; ++f) {
                    nxtA[f] = *(const short8*)(Zc + ko + offA[f]);
                    nxtB[f] = *(const short8*)(Zc + ko + offB[f]);
                }
            }
#pragma unroll
            for (int fi = 0; fi < 4; ++fi)
#pragma unroll
                for (int fj = 0; fj < 4; ++fj)
                    accf[fi][fj] = __builtin_amdgcn_mfma_f32_16x16x32_bf16(curA[fi], curB[fj], accf[fi][fj], 0, 0, 0);
            if (ck < 7) {
#pragma unroll
                for (int f = 0; f < 4; ++f) { curA[f] = nxtA[f]; curB[f] = nxtB[f]; }
            }
        }

        // ---- epilogue ----
        float c2[NSIG];
#pragma unroll
        for (int k = 0; k < NSIG; ++k) c2[k] = (-0.5f / sigmas[k]) * 1.44269504f;

        const float sgn2 = ((ti < 64) == (tj < 64)) ? 2.f : -2.f;

#pragma unroll
        for (int fi = 0; fi < 4; ++fi) {
            const floatx4 ni4 = *(const floatx4*)(norms + i0 + (fi << 4) + (q << 2));
#pragma unroll
            for (int fj = 0; fj < 4; ++fj) {
                const float njs = norms[j0 + (fj << 4) + m];
#pragma unroll
                for (int v = 0; v < 4; ++v) {
                    float d = fmaf(-2.f, accf[fi][fj][v], ni4[v] + njs);
                    d = fmaxf(d, 0.f);
                    if (diag) {
                        const int dif = ((fi - fj) << 4) + ((q << 2) + v) - m;   // gi - gj
                        d = (dif < 0) ? d : 3.0e9f;    // strictly-upper only
                    }
                    accf[fi][fj][v] = d;
                }
            }
        }

        float dmin = accf[0][0][0];
#pragma unroll
        for (int fi = 0; fi < 4; ++fi)
#pragma unroll
            for (int fj = 0; fj < 4; ++fj)
#pragma unroll
                for (int v = 0; v < 4; ++v) dmin = fminf(dmin, accf[fi][fj][v]);
#pragma unroll
        for (int off = 1; off < 64; off <<= 1) dmin = fminf(dmin, __shfl_xor(dmin, off, 64));

#pragma unroll
        for (int k = 0; k < NSIG; ++k) {
            if (c2[k] * dmin >= -126.f) {   // wave-uniform skip iff all exps underflow (exact in fp32)
#pragma unroll
                for (int fi = 0; fi < 4; ++fi)
#pragma unroll
                    for (int fj = 0; fj < 4; ++fj)
#pragma unroll
                        for (int v = 0; v < 4; ++v)
                            lsum += __builtin_amdgcn_exp2f(c2[k] * accf[fi][fj][v]);
            }
        }
        lsum *= sgn2;
    }

#pragma unroll
    for (int off = 32; off > 0; off >>= 1) lsum += __shfl_down(lsum, off, 64);
    if (l == 0) wsum[w] = lsum;
    __syncthreads();
    if (t == 0) partials[blockIdx.x] = wsum[0] + wsum[1] + wsum[2] + wsum[3];
}

__global__ __launch_bounds__(256) void finalize_kernel(const float* __restrict__ partials,
                                                       float* __restrict__ out) {
    __shared__ double sh[256];
    const int t = threadIdx.x;
    double s = 0.0;
    for (int i = t; i < NBLK2; i += 256) s += (double)partials[i];
    sh[t] = s;
    __syncthreads();
    for (int st = 128; st > 0; st >>= 1) {
        if (t < st) sh[t] += sh[t + st];
        __syncthreads();
    }
    if (t == 0) out[0] = (float)((sh[0] + 8192.0 * NSIG) * (1.0 / (4096.0 * 4096.0)));
}

extern "C" void kernel_launch(void* const* d_in, const int* in_sizes, int n_in,
                              void* d_out, int out_size, void* d_ws, size_t ws_size,
                              hipStream_t stream) {
    const float* x   = (const float*)d_in[0];
    const float* y   = (const float*)d_in[1];
    const float* sig = (const float*)d_in[2];

    ushort* Zc      = (ushort*)d_ws;                                   // 4 MiB
    float* norms    = (float*)((char*)d_ws + (size_t)8192 * 256 * 2);  // 32 KiB
    float* partials = (float*)((char*)norms + 8192 * sizeof(float));   // 2080 floats
    float* out      = (float*)d_out;

    prep_kernel<<<512, 256, 0, stream>>>(x, y, Zc, norms);
    gemm_epi<<<NBLK2, 256, 0, stream>>>(Zc, norms, sig, partials);
    finalize_kernel<<<1, 256, 0, stream>>>(partials, out);
}

// Round 2
// 96.671 us; speedup vs baseline: 1.0868x; 1.0868x over previous
//
#include <hip/hip_runtime.h>
#include <hip/hip_bf16.h>

// MMD loss via bf16 MFMA Gram matrix — barrier-free LDS-free GEMM core.
// R2: persistent-grid gemm (694 blocks, 1 balanced round instead of 2.7) with
// cross-tile software pipeline: next tile's chunk-0 loads are issued under the
// current tile's epilogue (norms pre-loaded first so the epilogue waitcnt does
// not drain the prefetch). Per-tile syncthreads reduce collapsed to one.
//
// Zc layout (R7): Zc[ck][row][32], stored quad = q ^ ((row>>1)&3); each mfma
// fragment = one contiguous coalesced 1KB block.
// Lessons: R4 no __threadfence in hot kernel; R5 no forced occupancy (spill);
// R6 no scattered vector loads; R3/R7 barrier-drain plateau.
//
// z = [xf; yf] (8192 x 256). result = (1/4096^2)*(8192*NSIG + sum_{i<j} 2 s_i s_j K_ij)
// ws: [0,4MiB) bf16 Zc; float norms[8192]; float partials[694].

#define NSIG 5
#define CKS   262144                 // chunk stride in ushorts: 8192 rows * 32
#define NBLK2 2080                   // 64-supergrid triangle: 64*65/2
#define GRIDP 694                    // persistent grid: 692 blocks x3 tiles + 2 x2

typedef __attribute__((ext_vector_type(8))) short short8;
typedef __attribute__((ext_vector_type(4))) float floatx4;

// ---- prep: (B,C,H,W) fp32 -> Zc chunked-swizzled bf16 + norms (unchanged) ----
__global__ __launch_bounds__(256) void prep_kernel(const float* __restrict__ x,
                                                   const float* __restrict__ y,
                                                   ushort* __restrict__ Zc,
                                                   float* __restrict__ norms) {
    const int bid = blockIdx.x;           // s(1) | b(2) | strip(6)
    const int t = threadIdx.x;
    const int s = bid >> 8;
    const int b = (bid >> 6) & 3;
    const int p0 = (bid & 63) << 4;
    const float* src = s ? y : x;
    const int n0 = (s << 12) + (b << 10) + p0;

    __shared__ float tile[256][17];

    const int cg = t >> 2;
    const int p4 = (t & 3) << 2;
#pragma unroll
    for (int pass = 0; pass < 4; ++pass) {
        const int c = cg + (pass << 6);
        const float4 v = *(const float4*)(src + (((size_t)((b << 8) + c)) << 10) + p0 + p4);
        tile[c][p4] = v.x; tile[c][p4 + 1] = v.y; tile[c][p4 + 2] = v.z; tile[c][p4 + 3] = v.w;
    }
    __syncthreads();

    const int r = t >> 4;
    const int q = t & 15;
    const int row = n0 + r;
    const int sw = (row >> 1) & 3;
    float nsum = 0.f;
#pragma unroll
    for (int h = 0; h < 2; ++h) {
        const int j = q + (h << 4);
        const int ck = j >> 2;
        const int sq = (j & 3) ^ sw;
        const int c0 = j << 3;
        uint pk[4];
#pragma unroll
        for (int jj = 0; jj < 4; ++jj) {
            const float f0 = tile[c0 + 2 * jj][r];
            const float f1 = tile[c0 + 2 * jj + 1][r];
            const __hip_bfloat16 h0 = __float2bfloat16(f0);
            const __hip_bfloat16 h1 = __float2bfloat16(f1);
            const float q0 = __bfloat162float(h0), q1 = __bfloat162float(h1);
            nsum = fmaf(q0, q0, nsum);
            nsum = fmaf(q1, q1, nsum);
            pk[jj] = (uint)(*(const ushort*)&h0) | ((uint)(*(const ushort*)&h1) << 16);
        }
        *(uint4*)(Zc + (size_t)ck * CKS + (size_t)row * 32 + (sq << 3)) =
            make_uint4(pk[0], pk[1], pk[2], pk[3]);
    }
#pragma unroll
    for (int off = 1; off < 16; off <<= 1) nsum += __shfl_xor(nsum, off, 32);
    if (q == 0) norms[row] = nsum;
}

// ---- tile decode: panel-ordered triangle (unchanged math) ----
__device__ __forceinline__ void decode_tile(int lin, int w, int& i0, int& j0,
                                            bool& active, bool& diag) {
    int p = (int)((-4.0f + sqrtf(16.0f + 128.0f * (float)lin)) * (1.0f / 64.0f));
    p = p < 0 ? 0 : (p > 7 ? 7 : p);
    while (p < 7 && 32 * (p + 1) * (p + 1) + 4 * (p + 1) <= lin) ++p;
    while (p > 0 && 32 * p * p + 4 * p > lin) --p;
    const int o = lin - (32 * p * p + 4 * p);
    int c = 7;
#pragma unroll
    for (int cc = 7; cc >= 1; --cc) {
        const int Q = cc * (8 * p + 1) + (cc * (cc - 1)) / 2;
        if (o < Q) c = cc - 1;
    }
    const int Qc = c * (8 * p + 1) + (c * (c - 1)) / 2;
    const int tj2 = 8 * p + c;
    const int ti2 = o - Qc;              // 0..tj2
    const int ti = (ti2 << 1) + (w >> 1);
    const int tj = (tj2 << 1) + (w & 1);
    active = (ti <= tj);
    diag = (ti == tj);
    i0 = ti << 6;
    j0 = tj << 6;
}

__device__ __forceinline__ void tile_offsets(int i0, int j0, int m, int q,
                                             int* offA, int* offB) {
#pragma unroll
    for (int f = 0; f < 4; ++f) {
        const int ra = i0 + (f << 4) + m;
        offA[f] = (ra << 5) + ((q ^ ((ra >> 1) & 3)) << 3);
        const int rb = j0 + (f << 4) + m;
        offB[f] = (rb << 5) + ((q ^ ((rb >> 1) & 3)) << 3);
    }
}

// ---- GEMM: persistent 2x2 wave-tile blocks, cross-tile pipelined ----
__global__ __launch_bounds__(256, 3) void gemm_epi(const ushort* __restrict__ Zc,
                                                   const float* __restrict__ norms,
                                                   const float* __restrict__ sigmas,
                                                   float* __restrict__ partials) {
    __shared__ float wsum[4];

    const int t = threadIdx.x;
    const int w = t >> 6, l = t & 63;
    const int m = l & 15, q = l >> 4;

    float c2[NSIG];
#pragma unroll
    for (int k = 0; k < NSIG; ++k) c2[k] = (-0.5f / sigmas[k]) * 1.44269504f;

    int lin = blockIdx.x;
    int i0, j0;
    bool active, diag;
    decode_tile(lin, w, i0, j0, active, diag);
    int offA[4], offB[4];
    tile_offsets(i0, j0, m, q, offA, offB);

    short8 curA[4], curB[4];
#pragma unroll
    for (int f = 0; f < 4; ++f) {
        curA[f] = *(const short8*)(Zc + offA[f]);
        curB[f] = *(const short8*)(Zc + offB[f]);
    }

    float lsum = 0.f;

#pragma unroll 1
    for (;;) {
        floatx4 accf[4][4];
#pragma unroll
        for (int fi = 0; fi < 4; ++fi)
#pragma unroll
            for (int fj = 0; fj < 4; ++fj) accf[fi][fj] = (floatx4){0.f, 0.f, 0.f, 0.f};

        // ---- main K loop: 8 chunks, 1-deep in-loop prefetch ----
        short8 nxtA[4], nxtB[4];
#pragma unroll
        for (int ck = 0; ck < 8; ++ck) {
            if (ck < 7) {
                const size_t ko = (size_t)(ck + 1) * CKS;
#pragma unroll
                for (int f = 0; f < 4; ++f) {
                    nxtA[f] = *(const short8*)(Zc + ko + offA[f]);
                    nxtB[f] = *(const short8*)(Zc + ko + offB[f]);
                }
            }
#pragma unroll
            for (int fi = 0; fi < 4; ++fi)
#pragma unroll
                for (int fj = 0; fj < 4; ++fj)
                    accf[fi][fj] = __builtin_amdgcn_mfma_f32_16x16x32_bf16(curA[fi], curB[fj], accf[fi][fj], 0, 0, 0);
            if (ck < 7) {
#pragma unroll
                for (int f = 0; f < 4; ++f) { curA[f] = nxtA[f]; curB[f] = nxtB[f]; }
            }
        }

        // ---- save current-tile epilogue context ----
        const int ei0 = i0, ej0 = j0;
        const bool eact = active, ediag = diag;
        const float esgn2 = ((ei0 < 4096) == (ej0 < 4096)) ? 2.f : -2.f;

        // ---- norms FIRST (so epilogue waitcnt doesn't drain next prefetch) ----
        floatx4 ni4[4];
        float njs[4];
#pragma unroll
        for (int fi = 0; fi < 4; ++fi)
            ni4[fi] = *(const floatx4*)(norms + ei0 + (fi << 4) + (q << 2));
#pragma unroll
        for (int fj = 0; fj < 4; ++fj)
            njs[fj] = norms[ej0 + (fj << 4) + m];

        // ---- issue next tile's chunk-0 prologue under this epilogue ----
        const int lin2 = lin + GRIDP;
        const bool have2 = (lin2 < NBLK2);
        if (have2) {
            decode_tile(lin2, w, i0, j0, active, diag);
            tile_offsets(i0, j0, m, q, offA, offB);
#pragma unroll
            for (int f = 0; f < 4; ++f) {
                curA[f] = *(const short8*)(Zc + offA[f]);
                curB[f] = *(const short8*)(Zc + offB[f]);
            }
        }

        // ---- epilogue (wave-uniform active flag) ----
        if (eact) {
#pragma unroll
            for (int fi = 0; fi < 4; ++fi) {
#pragma unroll
                for (int fj = 0; fj < 4; ++fj) {
#pragma unroll
                    for (int v = 0; v < 4; ++v) {
                        float d = fmaf(-2.f, accf[fi][fj][v], ni4[fi][v] + njs[fj]);
                        d = fmaxf(d, 0.f);
                        if (ediag) {
                            const int dif = ((fi - fj) << 4) + ((q << 2) + v) - m;   // gi - gj
                            d = (dif < 0) ? d : 3.0e9f;    // strictly-upper only
                        }
                        accf[fi][fj][v] = d;
                    }
                }
            }

            float dmin = accf[0][0][0];
#pragma unroll
            for (int fi = 0; fi < 4; ++fi)
#pragma unroll
                for (int fj = 0; fj < 4; ++fj)
#pragma unroll
                    for (int v = 0; v < 4; ++v) dmin = fminf(dmin, accf[fi][fj][v]);
#pragma unroll
            for (int off = 1; off < 64; off <<= 1) dmin = fminf(dmin, __shfl_xor(dmin, off, 64));

            float tsum = 0.f;
#pragma unroll
            for (int k = 0; k < NSIG; ++k) {
                if (c2[k] * dmin >= -126.f) {   // wave-uniform skip iff all exps underflow
#pragma unroll
                    for (int fi = 0; fi < 4; ++fi)
#pragma unroll
                        for (int fj = 0; fj < 4; ++fj)
#pragma unroll
                            for (int v = 0; v < 4; ++v)
                                tsum += __builtin_amdgcn_exp2f(c2[k] * accf[fi][fj][v]);
                }
            }
            lsum = fmaf(esgn2, tsum, lsum);
        }

        lin = lin2;
        if (!have2) break;
    }

    // ---- once-per-block reduce + store ----
#pragma unroll
    for (int off = 32; off > 0; off >>= 1) lsum += __shfl_down(lsum, off, 64);
    if (l == 0) wsum[w] = lsum;
    __syncthreads();
    if (t == 0) partials[blockIdx.x] = wsum[0] + wsum[1] + wsum[2] + wsum[3];
}

__global__ __launch_bounds__(256) void finalize_kernel(const float* __restrict__ partials,
                                                       float* __restrict__ out) {
    __shared__ double sh[256];
    const int t = threadIdx.x;
    double s = 0.0;
    for (int i = t; i < GRIDP; i += 256) s += (double)partials[i];
    sh[t] = s;
    __syncthreads();
    for (int st = 128; st > 0; st >>= 1) {
        if (t < st) sh[t] += sh[t + st];
        __syncthreads();
    }
    if (t == 0) out[0] = (float)((sh[0] + 8192.0 * NSIG) * (1.0 / (4096.0 * 4096.0)));
}

extern "C" void kernel_launch(void* const* d_in, const int* in_sizes, int n_in,
                              void* d_out, int out_size, void* d_ws, size_t ws_size,
                              hipStream_t stream) {
    const float* x   = (const float*)d_in[0];
    const float* y   = (const float*)d_in[1];
    const float* sig = (const float*)d_in[2];

    ushort* Zc      = (ushort*)d_ws;                                   // 4 MiB
    float* norms    = (float*)((char*)d_ws + (size_t)8192 * 256 * 2);  // 32 KiB
    float* partials = (float*)((char*)norms + 8192 * sizeof(float));   // 694 floats
    float* out      = (float*)d_out;

    prep_kernel<<<512, 256, 0, stream>>>(x, y, Zc, norms);
    gemm_epi<<<GRIDP, 256, 0, stream>>>(Zc, norms, sig, partials);
    finalize_kernel<<<1, 256, 0, stream>>>(partials, out);
}